// Round 2
// baseline (1786.124 us; speedup 1.0000x reference)
//
#include <hip/hip_runtime.h>

#define NB 64
#define NT 4096
#define NS 128
#define TILE 32
#define NTILES (NT / TILE)   // 128
#define NTH 512
#define GRP 40               // padded group stride: 32 floats + 8 pad -> banks 0/8/16/24

typedef float v2f __attribute__((ext_vector_type(2)));

__global__ __launch_bounds__(NTH)
void crf_fwd(const float* __restrict__ obs,
             const float* __restrict__ trans,
             float* __restrict__ out)
{
    __shared__ float Pbuf[2][4 * GRP];           // P state, double-buffered, padded
    __shared__ float obsT[TILE * NS];            // 32-step tile of exp(obs)
    __shared__ __align__(16) float wmax[8];      // per-wave maxes for renorm

    const int tid = threadIdx.x;
    const int w   = tid >> 6;             // wave 0..7
    const int l   = tid & 63;             // lane
    const int j   = (w << 4) + (l >> 2);  // owned to-state 0..127
    const int sub = l & 3;                // i-slice 0..3 (32 rows each)

    // expA column slice -> registers as float2 pairs (one-time, A is constant)
    v2f ea[16];
    {
        const float* tc = trans + j;
        #pragma unroll
        for (int k = 0; k < 16; ++k) {
            v2f e;
            e.x = __expf(tc[(sub * 32 + 2 * k + 0) * NS]);
            e.y = __expf(tc[(sub * 32 + 2 * k + 1) * NS]);
            ea[k] = e;
        }
    }

    const float* obsB = obs + (size_t)blockIdx.x * NT * NS;

    // prefetch tile 0 into registers
    {
    }
    const float4* g0 = (const float4*)obsB;
    float4 r0 = g0[tid];
    float4 r1 = g0[tid + NTH];

    float L = 0.f;          // accumulated log-scale (uniform across block)
    float eo_next = 0.f;    // exp(obs[t][j]) for the upcoming step

    for (int tile = 0; tile < NTILES; ++tile) {
        // stage current tile's exp(obs) (regs -> LDS), then prefetch next tile
        float4 e0, e1;
        e0.x = __expf(r0.x); e0.y = __expf(r0.y); e0.z = __expf(r0.z); e0.w = __expf(r0.w);
        e1.x = __expf(r1.x); e1.y = __expf(r1.y); e1.z = __expf(r1.z); e1.w = __expf(r1.w);
        ((float4*)obsT)[tid]       = e0;
        ((float4*)obsT)[tid + NTH] = e1;
        if (tile + 1 < NTILES) {
            const float4* gn = (const float4*)(obsB + (size_t)(tile + 1) * TILE * NS);
            r0 = gn[tid];
            r1 = gn[tid + NTH];
        }
        __syncthreads();

        int tt_start = 0;
        if (tile == 0) {
            // peeled step 0: P0[j] = exp(obs0[j])
            float Pn = obsT[j];
            if (sub == 0) Pbuf[0][((j >> 5) * GRP) + (j & 31)] = Pn;
            eo_next = obsT[NS + j];
            tt_start = 1;
            __syncthreads();
        } else {
            eo_next = obsT[j];
        }

        for (int tt = tt_start; tt < TILE; ++tt) {
            const int t = tile * TILE + tt;
            const bool ren = ((t & 3) == 0);

            // renorm inputs: issue LDS reads immediately (overlap with dot)
            float4 wa, wb;
            if (ren) {
                wa = ((const float4*)wmax)[0];
                wb = ((const float4*)wmax)[1];
            }

            // quarter-dot over i in [32*sub, 32*sub+32), 4 parallel packed chains
            const v2f* P2 = (const v2f*)&Pbuf[(t + 1) & 1][sub * GRP];
            v2f a0 = {0.f, 0.f}, a1 = {0.f, 0.f}, a2 = {0.f, 0.f}, a3 = {0.f, 0.f};
            #pragma unroll
            for (int k = 0; k < 4; ++k) {
                a0 = __builtin_elementwise_fma(P2[4 * k + 0], ea[4 * k + 0], a0);
                a1 = __builtin_elementwise_fma(P2[4 * k + 1], ea[4 * k + 1], a1);
                a2 = __builtin_elementwise_fma(P2[4 * k + 2], ea[4 * k + 2], a2);
                a3 = __builtin_elementwise_fma(P2[4 * k + 3], ea[4 * k + 3], a3);
            }

            float eo = eo_next;
            if (tt < TILE - 1) eo_next = obsT[(tt + 1) * NS + j];  // pipeline next eo

            if (ren) {
                // finish renorm off the dot's critical path; fold scale into eo
                float M = fmaxf(fmaxf(fmaxf(wa.x, wa.y), fmaxf(wa.z, wa.w)),
                                fmaxf(fmaxf(wb.x, wb.y), fmaxf(wb.z, wb.w)));
                L += __logf(M);
                eo *= __builtin_amdgcn_rcpf(M);
            }

            v2f s2 = (a0 + a1) + (a2 + a3);
            float sp = s2.x + s2.y;
            sp += __shfl_xor(sp, 1);   // combine 4 sub-partials (quad DPP)
            sp += __shfl_xor(sp, 2);

            const float Pn = sp * eo;

            if ((t & 3) == 3) {
                // measure max over all 128 P' (all 4 lanes/group hold same Pn)
                float m = Pn;
                m = fmaxf(m, __shfl_xor(m, 4));
                m = fmaxf(m, __shfl_xor(m, 8));
                m = fmaxf(m, __shfl_xor(m, 16));
                m = fmaxf(m, __shfl_xor(m, 32));
                if (l == 0) wmax[w] = m;
            }
            if (sub == 0)
                Pbuf[t & 1][((j >> 5) * GRP) + (j & 31)] = Pn;
            __syncthreads();
        }
    }

    // epilogue: out[b] = -(log(sum_j P[j]) + L); final P is in Pbuf[1] (t=4095 odd)
    if (tid < 64) {
        const float* Pf = Pbuf[1];
        float a  = Pf[((tid >> 5) * GRP) + (tid & 31)];
        const int i2 = tid + 64;
        float b2 = Pf[((i2 >> 5) * GRP) + (i2 & 31)];
        float ssum = a + b2;
        ssum += __shfl_xor(ssum, 1);
        ssum += __shfl_xor(ssum, 2);
        ssum += __shfl_xor(ssum, 4);
        ssum += __shfl_xor(ssum, 8);
        ssum += __shfl_xor(ssum, 16);
        ssum += __shfl_xor(ssum, 32);
        if (tid == 0) out[blockIdx.x] = -(__logf(ssum) + L);
    }
}

extern "C" void kernel_launch(void* const* d_in, const int* in_sizes, int n_in,
                              void* d_out, int out_size, void* d_ws, size_t ws_size,
                              hipStream_t stream) {
    const float* obs   = (const float*)d_in[0];   // [64, 4096, 128] fp32
    const float* trans = (const float*)d_in[1];   // [128, 128] fp32
    float* out = (float*)d_out;                   // [64] fp32
    hipLaunchKernelGGL(crf_fwd, dim3(NB), dim3(NTH), 0, stream, obs, trans, out);
}

// Round 3
// 1183.990 us; speedup vs baseline: 1.5086x; 1.5086x over previous
//
#include <hip/hip_runtime.h>

typedef _Float16 h2f __attribute__((ext_vector_type(2)));
typedef unsigned int uint32;

#define TILE 16
#define NTILE 128                     // 2048 steps per half
#define SHIFT 2.0794415416798357f     // log(8), folded into every eo, repaid in L

__device__ __forceinline__ h2f u2h(uint32 u) { return __builtin_bit_cast(h2f, u); }
__device__ __forceinline__ uint32 f2h(float f) {
    return (uint32)__builtin_bit_cast(unsigned short, (_Float16)f);
}

#if __has_builtin(__builtin_amdgcn_fdot2)
#define FDOT2(p, e, acc) __builtin_amdgcn_fdot2((p), (e), (acc), false)
#else
#define FDOT2(p, e, acc) fmaf((float)(p).x, (float)(e).x, fmaf((float)(p).y, (float)(e).y, (acc)))
#endif

// One recurrence step. Wave-local: the wave-wide ds_write of Pl is seen by the
// broadcast ds_reads that follow (in-order DS pipe, single wave, no barrier).
#define STEP(N0, APPLY, MEAS)  do {                                                 \
    const int row_ = fw ? ((N0) & (TILE - 1)) : ((TILE - 1) - ((N0) & (TILE - 1))); \
    const float2 o2_ = *(const float2*)&obsL[(((N0) >> 4) & 1) * (TILE * 128) + (row_ << 7) + (l << 1)]; \
    float e0_ = __expf(o2_.x - SHIFT);                                              \
    float e1_ = __expf(o2_.y - SHIFT);                                              \
    if (APPLY) { e0_ *= rs; e1_ *= rs; }                                            \
    float w0_, w1_;                                                                 \
    if (fw) { w0_ = pv0; w1_ = pv1; } else { w0_ = pv0 * e0_; w1_ = pv1 * e1_; }    \
    Pl[l] = (f2h(w1_) << 16) | f2h(w0_);                                            \
    float a0_=0.f,a1_=0.f,a2_=0.f,a3_=0.f,b0_=0.f,b1_=0.f,b2_=0.f,b3_=0.f;          \
    _Pragma("unroll")                                                               \
    for (int c_ = 0; c_ < 16; ++c_) {                                               \
        const uint4 q_ = ((const uint4*)Pl)[c_];                                    \
        const h2f p0_ = u2h(q_.x), p1_ = u2h(q_.y), p2_ = u2h(q_.z), p3_ = u2h(q_.w); \
        a0_ = FDOT2(p0_, eA[4*c_+0], a0_);                                          \
        a1_ = FDOT2(p1_, eA[4*c_+1], a1_);                                          \
        a2_ = FDOT2(p2_, eA[4*c_+2], a2_);                                          \
        a3_ = FDOT2(p3_, eA[4*c_+3], a3_);                                          \
        b0_ = FDOT2(p0_, eB[4*c_+0], b0_);                                          \
        b1_ = FDOT2(p1_, eB[4*c_+1], b1_);                                          \
        b2_ = FDOT2(p2_, eB[4*c_+2], b2_);                                          \
        b3_ = FDOT2(p3_, eB[4*c_+3], b3_);                                          \
    }                                                                               \
    const float s0_ = (a0_ + a1_) + (a2_ + a3_);                                    \
    const float s1_ = (b0_ + b1_) + (b2_ + b3_);                                    \
    if (fw) { pv0 = s0_ * e0_; pv1 = s1_ * e1_; } else { pv0 = s0_; pv1 = s1_; }    \
    if (MEAS) {                                                                     \
        float m_ = fmaxf(pv0, pv1);                                                 \
        m_ = fmaxf(m_, __shfl_xor(m_, 1));                                          \
        m_ = fmaxf(m_, __shfl_xor(m_, 2));                                          \
        m_ = fmaxf(m_, __shfl_xor(m_, 4));                                          \
        m_ = fmaxf(m_, __shfl_xor(m_, 8));                                          \
        m_ = fmaxf(m_, __shfl_xor(m_, 16));                                         \
        m_ = fmaxf(m_, __shfl_xor(m_, 32));                                         \
        rs = __builtin_amdgcn_rcpf(m_);                                             \
        Lacc += __logf(m_);                                                         \
    }                                                                               \
} while (0)

#define LOADR(TK) do {                                                              \
    const float4* g_ = (const float4*)(obsB + (size_t)(fw ? (TK) * (TILE * 128)     \
                                      : (4096 - TILE * ((TK) + 1)) * 128));         \
    r0 = g_[l];       r1 = g_[l + 64];  r2 = g_[l + 128]; r3 = g_[l + 192];         \
    r4 = g_[l + 256]; r5 = g_[l + 320]; r6 = g_[l + 384]; r7 = g_[l + 448];         \
} while (0)

#define STORER(TK) do {                                                             \
    float4* s_ = (float4*)&obsL[((TK) & 1) * (TILE * 128)];                         \
    s_[l] = r0;       s_[l + 64] = r1;  s_[l + 128] = r2; s_[l + 192] = r3;         \
    s_[l + 256] = r4; s_[l + 320] = r5; s_[l + 384] = r6; s_[l + 448] = r7;         \
} while (0)

__global__ __launch_bounds__(64, 1)
void crf_half(const float* __restrict__ obs, const float* __restrict__ trans,
              float* __restrict__ ws)
{
    __shared__ __align__(16) uint32 Pl[64];            // 128 fp16 state values
    __shared__ __align__(16) float obsL[2 * TILE * 128];

    const int l  = threadIdx.x;
    const bool fw = blockIdx.x < 64;
    const int b  = fw ? blockIdx.x : blockIdx.x - 64;
    const float* obsB = obs + (size_t)b * 4096 * 128;

    // exp(A) fragments, fp16 pairs along the dot axis. fwd: columns 2l,2l+1.
    // bwd: rows 2l,2l+1 (row-dot for the backward recurrence).
    h2f eA[64], eB[64];
    if (fw) {
        const int c0 = 2 * l;
        #pragma unroll
        for (int k = 0; k < 64; ++k) {
            h2f ta, tb;
            ta.x = (_Float16)__expf(trans[(2*k    ) * 128 + c0]);
            ta.y = (_Float16)__expf(trans[(2*k + 1) * 128 + c0]);
            tb.x = (_Float16)__expf(trans[(2*k    ) * 128 + c0 + 1]);
            tb.y = (_Float16)__expf(trans[(2*k + 1) * 128 + c0 + 1]);
            eA[k] = ta; eB[k] = tb;
        }
    } else {
        const int ro0 = (2 * l) * 128, ro1 = (2 * l + 1) * 128;
        #pragma unroll
        for (int k = 0; k < 64; ++k) {
            h2f ta, tb;
            ta.x = (_Float16)__expf(trans[ro0 + 2*k]);
            ta.y = (_Float16)__expf(trans[ro0 + 2*k + 1]);
            tb.x = (_Float16)__expf(trans[ro1 + 2*k]);
            tb.y = (_Float16)__expf(trans[ro1 + 2*k + 1]);
            eA[k] = ta; eB[k] = tb;
        }
    }

    float4 r0, r1, r2, r3, r4, r5, r6, r7;
    LOADR(0);
    STORER(0);
    LOADR(1);

    float rs = 1.f, Lacc = 0.f, pv0, pv1;

    // peel step n=0. fwd: P0 = exp(obs0 - SHIFT). bwd: Q_4095 = 1, full step (t=4095).
    if (fw) {
        const float2 o2 = *(const float2*)&obsL[l << 1];   // buf 0, row 0
        pv0 = __expf(o2.x - SHIFT);
        pv1 = __expf(o2.y - SHIFT);
    } else {
        pv0 = 1.f; pv1 = 1.f;
        STEP(0, false, false);
    }

    for (int tile = 0; tile < NTILE; ++tile) {
        if (tile > 0) {
            STORER(tile);                       // r holds tile's data (vmcnt dep)
            if (tile < NTILE - 1) LOADR(tile + 1);
        }
        const int nb = tile << 4;
        #pragma unroll 1
        for (int g = 0; g < 4; ++g) {
            const int n0 = nb + (g << 2);
            if (n0 > 0) STEP(n0, true, false);          // n%4==0: apply pending renorm
            STEP(n0 + 1, false, false);
            STEP(n0 + 2, false, false);
            if (n0 + 3 != 2047) STEP(n0 + 3, false, true);   // n%4==3: measure
            else                STEP(n0 + 3, false, false);  // final step: no measure
        }
    }

    // epilogue: halves to workspace. ws: Pm[64][128] | Qm[64][128] | Lf[64] | Lb[64]
    if (fw) {
        ws[b * 128 + 2*l]     = pv0;
        ws[b * 128 + 2*l + 1] = pv1;
        if (l == 0) ws[16384 + b] = Lacc;
    } else {
        ws[8192 + b * 128 + 2*l]     = pv0;
        ws[8192 + b * 128 + 2*l + 1] = pv1;
        if (l == 0) ws[16448 + b] = Lacc;
    }
}

__global__ __launch_bounds__(64)
void crf_combine(const float* __restrict__ ws, float* __restrict__ out)
{
    const int b = blockIdx.x, l = threadIdx.x;
    const float* Pm = ws;
    const float* Qm = ws + 8192;
    float s = Pm[b * 128 + 2*l] * Qm[b * 128 + 2*l]
            + Pm[b * 128 + 2*l + 1] * Qm[b * 128 + 2*l + 1];
    s += __shfl_xor(s, 1);
    s += __shfl_xor(s, 2);
    s += __shfl_xor(s, 4);
    s += __shfl_xor(s, 8);
    s += __shfl_xor(s, 16);
    s += __shfl_xor(s, 32);
    if (l == 0)
        out[b] = -(__logf(s) + ws[16384 + b] + ws[16448 + b] + 4096.0f * SHIFT);
}

extern "C" void kernel_launch(void* const* d_in, const int* in_sizes, int n_in,
                              void* d_out, int out_size, void* d_ws, size_t ws_size,
                              hipStream_t stream) {
    const float* obs   = (const float*)d_in[0];   // [64, 4096, 128] fp32
    const float* trans = (const float*)d_in[1];   // [128, 128] fp32
    float* out = (float*)d_out;                   // [64] fp32
    float* ws  = (float*)d_ws;                    // >= 16512 floats
    hipLaunchKernelGGL(crf_half,    dim3(128), dim3(64), 0, stream, obs, trans, ws);
    hipLaunchKernelGGL(crf_combine, dim3(64),  dim3(64), 0, stream, ws, out);
}